// Round 8
// baseline (116.726 us; speedup 1.0000x reference)
//
#include <hip/hip_runtime.h>
#include <hip/hip_bf16.h>

#define N 8192
#define D 128
#define LN2 0.69314718056f

typedef __bf16 bf16x8 __attribute__((ext_vector_type(8)));
typedef float f32x4 __attribute__((ext_vector_type(4)));
typedef unsigned int u32;

// async global->LDS, 16B/lane; LDS dest = wave-uniform base + lane*16,
// global src per-lane (m173: swizzle lives on the SOURCE address).
__device__ __forceinline__ void gload_lds16(const void* g, void* l) {
    __builtin_amdgcn_global_load_lds(
        (const __attribute__((address_space(1))) u32*)g,
        (__attribute__((address_space(3))) u32*)l, 16, 0, 0);
}

// Kernel 1: row-normalize (fp32 -> bf16), pre-scaled by rsqrt(T*ln2) so
// downstream dot products equal logits*log2(e). Exact-integer label
// histogram via fp32 atomics (deterministic). Zeroes tail counter.
__global__ void k_norm(const float* __restrict__ feat, const int* __restrict__ lab,
                       const float* __restrict__ tempp,
                       __hip_bfloat16* __restrict__ fbf, float* __restrict__ hist,
                       unsigned* __restrict__ counter) {
    if (blockIdx.x == 0 && threadIdx.x == 0) *counter = 0u;
    const int row  = blockIdx.x * 4 + (threadIdx.x >> 6);
    const int lane = threadIdx.x & 63;
    float2 v = *reinterpret_cast<const float2*>(&feat[row * D + lane * 2]);
    float ss = v.x * v.x + v.y * v.y;
#pragma unroll
    for (int m = 32; m; m >>= 1) ss += __shfl_xor(ss, m);
    const float sc = rsqrtf(tempp[0] * LN2);
    const float r = sc / fmaxf(sqrtf(ss), 1e-8f);
    __hip_bfloat162 o;
    o.x = __float2bfloat16(v.x * r);
    o.y = __float2bfloat16(v.y * r);
    *reinterpret_cast<__hip_bfloat162*>(&fbf[row * D + lane * 2]) = o;
    if (lane == 0) atomicAdd(&hist[lab[row]], 1.0f);
}

// Kernel 2a: one-pass class-sum scatter. Block ch owns 32 rows; thread tid
// owns dim tid EXCLUSIVELY -> LDS Sl[100][128] accumulate with no atomics,
// fixed order (deterministic). 2-way bank aliasing only (free, m136).
__global__ void k_csum(const __hip_bfloat16* __restrict__ fbf, const int* __restrict__ lab,
                       float* __restrict__ S_part) {
    __shared__ float Sl[100 * 128];
    __shared__ int labL[32];
    const int ch = blockIdx.x, tid = threadIdx.x;   // 256 blocks x 128 threads
#pragma unroll
    for (int k = 0; k < 100; ++k) Sl[k * 128 + tid] = 0.0f;
    if (tid < 32) labL[tid] = lab[ch * 32 + tid];
    __syncthreads();
    float v[32];
#pragma unroll
    for (int r = 0; r < 32; ++r)                    // independent, pipelined
        v[r] = __bfloat162float(fbf[(size_t)(ch * 32 + r) * D + tid]);
#pragma unroll
    for (int r = 0; r < 32; ++r)                    // serial per-thread chain
        Sl[labL[r] * 128 + tid] += v[r];
    // thread tid is the only writer of column tid -> no sync needed
#pragma unroll
    for (int k = 0; k < 100; ++k)
        S_part[(size_t)ch * 12800 + k * 128 + tid] = Sl[k * 128 + tid];
}

// Kernel 2b: combine 256 chunk partials -> S[100][128].
__global__ void k_csum2(const float* __restrict__ S_part, float* __restrict__ S) {
    const int c = blockIdx.x, tid = threadIdx.x;
    float s = 0.0f;
#pragma unroll 8
    for (int ch = 0; ch < 256; ++ch) s += S_part[(size_t)ch * 12800 + c * 128 + tid];
    S[(size_t)c * 128 + tid] = s;
}

// Kernel 3: balanced upper-triangle strips (UNCHANGED from R7).
__launch_bounds__(256, 2)
__global__ void k_gemm(const __hip_bfloat16* __restrict__ fbf,
                       const int* __restrict__ lab,
                       float* __restrict__ ProwE, float* __restrict__ PcolE) {
    __shared__ char Bs[65536];                 // 2 x 32KB B-tile buffers
    __shared__ float redC[2][2][128];          // [parity][wm][col]

    int bid = blockIdx.x, g = 0;
    while (bid >= 4 * (16 - g)) { bid -= 4 * (16 - g); ++g; }
    const int na = 16 - g;
    int a = 4 * g, seg = bid;
    while (seg >= na) { seg -= na; ++a; }
    const int bstart = a + seg * 4;
    const int nt = min(4, 64 - bstart);

    const int i0 = a * 128;
    const int tid = threadIdx.x;
    const int wave = tid >> 6, lane = tid & 63;
    const int wm = wave >> 1, wn = wave & 1;
    const int lr = lane & 15, lg = lane >> 4;

    const __hip_bfloat16* pa = fbf + (size_t)(i0 + wm * 64 + lr) * D + lg * 8;
    bf16x8 af[4][4];
#pragma unroll
    for (int mi = 0; mi < 4; ++mi)
#pragma unroll
        for (int ks = 0; ks < 4; ++ks)
            af[mi][ks] = *reinterpret_cast<const bf16x8*>(pa + mi * 16 * D + ks * 32);

    int4 labi[4];
#pragma unroll
    for (int mi = 0; mi < 4; ++mi)
        labi[mi] = *reinterpret_cast<const int4*>(&lab[i0 + wm * 64 + mi * 16 + lg * 4]);

    float res_[4][4] = {};

    const char* fbytes = reinterpret_cast<const char*>(fbf);
#define STAGE(t)                                                               \
    {                                                                          \
        const int j0s = (bstart + (t)) * 128;                                  \
        char* dst = Bs + ((t) & 1) * 32768;                                    \
        _Pragma("unroll")                                                      \
        for (int it = 0; it < 8; ++it) {                                       \
            const int base = (it * 4 + wave) * 64;                             \
            const int c_ = base + lane;                                        \
            const int row = c_ >> 4;                                           \
            const int kc = (c_ & 15) ^ (row & 7);                              \
            gload_lds16(fbytes + (size_t)(j0s + row) * 256 + kc * 16,          \
                        dst + base * 16);                                      \
        }                                                                      \
    }

    STAGE(0);
    __syncthreads();

    for (int t = 0; t < nt; ++t) {
        if (t + 1 < nt) STAGE(t + 1);
        const char* buf = Bs + (t & 1) * 32768;
        const int bt = bstart + t;
        const int j0 = bt * 128;
        float ces[2][2] = {};
#pragma unroll
        for (int h = 0; h < 2; ++h) {
            bf16x8 bfr[2][4];
            int labj[2];
#pragma unroll
            for (int nih = 0; nih < 2; ++nih) {
#pragma unroll
                for (int ks = 0; ks < 4; ++ks) {
                    const int R = wn * 64 + h * 32 + nih * 16 + lr;
                    const int kc = ks * 4 + lg;
                    bfr[nih][ks] = *reinterpret_cast<const bf16x8*>(
                        buf + R * 256 + ((kc ^ (R & 7)) << 4));
                }
                labj[nih] = lab[j0 + wn * 64 + h * 32 + nih * 16 + lr];
            }
            f32x4 acc[4][2] = {};
#pragma unroll
            for (int ks = 0; ks < 4; ++ks)
#pragma unroll
                for (int mi = 0; mi < 4; ++mi)
#pragma unroll
                    for (int nih = 0; nih < 2; ++nih)
                        acc[mi][nih] = __builtin_amdgcn_mfma_f32_16x16x32_bf16(
                            af[mi][ks], bfr[nih][ks], acc[mi][nih], 0, 0, 0);
            // C/D layout (m89): col = lane&15, row = (lane>>4)*4 + reg
#pragma unroll
            for (int mi = 0; mi < 4; ++mi)
#pragma unroll
                for (int r = 0; r < 4; ++r) {
                    const int li = reinterpret_cast<const int*>(&labi[mi])[r];
#pragma unroll
                    for (int nih = 0; nih < 2; ++nih) {
                        const float e = __builtin_amdgcn_exp2f(acc[mi][nih][r]);
                        const float em = (li == labj[nih]) ? 0.0f : e;
                        res_[mi][r] += em;     // row path
                        ces[h][nih] += em;     // col path (static idx)
                    }
                }
        }
#pragma unroll
        for (int h = 0; h < 2; ++h)
#pragma unroll
            for (int nih = 0; nih < 2; ++nih) {
                float ce = ces[h][nih];
                ce += __shfl_xor(ce, 16);
                ce += __shfl_xor(ce, 32);
                if (lg == 0) redC[t & 1][wm][wn * 64 + h * 32 + nih * 16 + lr] = ce;
            }
        __syncthreads();   // dbuf handoff + redC visibility
        if (tid < 128 && bt != a)
            PcolE[(size_t)a * N + j0 + tid] = redC[t & 1][0][tid] + redC[t & 1][1][tid];
    }
#undef STAGE

#pragma unroll
    for (int mi = 0; mi < 4; ++mi)
#pragma unroll
        for (int r = 0; r < 4; ++r) {
            float es = res_[mi][r];
#pragma unroll
            for (int m = 1; m < 16; m <<= 1) es += __shfl_xor(es, m);
            if (lr == 0) {
                const int rowl = wm * 64 + mi * 16 + lg * 4 + r;
                ProwE[(size_t)(seg * 2 + wn) * N + i0 + rowl] = es;
            }
        }
}

// Kernel 4: per-row combine, sp via class-sum dot, cnt via hist,
// block sums, last-block finalize (deterministic).
__global__ void k_tail(const float* __restrict__ ProwE, const float* __restrict__ PcolE,
                       const __hip_bfloat16* __restrict__ fbf, const int* __restrict__ lab,
                       const float* __restrict__ S, const float* __restrict__ hist,
                       float* __restrict__ bsums, unsigned* __restrict__ counter,
                       float* __restrict__ out) {
    const int tid = threadIdx.x;
    const int i = blockIdx.x * 256 + tid;
    const int p = i >> 7;
    const int c = lab[i];
    float ed = 0.0f;
    const int ns = 16 - (p >> 2);
    for (int s = 0; s < ns; ++s)
        ed += ProwE[(size_t)(2 * s) * N + i] + ProwE[(size_t)(2 * s + 1) * N + i];
    for (int aa = 0; aa < p; ++aa)
        ed += PcolE[(size_t)aa * N + i];
    float sp = 0.0f;
    const __hip_bfloat16* fr = fbf + (size_t)i * D;
    const float* Sc = S + (size_t)c * 128;
#pragma unroll
    for (int d = 0; d < 128; d += 8) {
        bf16x8 v = *reinterpret_cast<const bf16x8*>(fr + d);
#pragma unroll
        for (int k = 0; k < 8; ++k) sp += (float)v[k] * Sc[d + k];
    }
    float term = LN2 * (sp / hist[c] - __builtin_amdgcn_logf(ed));  // log2 -> ln
#pragma unroll
    for (int m = 32; m; m >>= 1) term += __shfl_xor(term, m);
    __shared__ float wsum[4];
    if ((tid & 63) == 0) wsum[tid >> 6] = term;
    __syncthreads();
    if (tid == 0) {
        bsums[blockIdx.x] = wsum[0] + wsum[1] + wsum[2] + wsum[3];
        __threadfence();
        const unsigned v = atomicAdd(counter, 1u);
        if (v == 31u) {
            __threadfence();
            float tt = 0.0f;
            for (int k = 0; k < 32; ++k) tt += bsums[k];
            out[0] = -(tt / (float)N);
        }
    }
}

extern "C" void kernel_launch(void* const* d_in, const int* in_sizes, int n_in,
                              void* d_out, int out_size, void* d_ws, size_t ws_size,
                              hipStream_t stream) {
    const float* feat = (const float*)d_in[0];
    const int* lab    = (const int*)d_in[1];
    const float* temp = (const float*)d_in[2];
    float* out = (float*)d_out;
    char* ws = (char*)d_ws;

    __hip_bfloat16* fbf = (__hip_bfloat16*)ws;     // 2 MB scaled bf16 features
    float* ProwE  = (float*)(ws + 2097152);        // 1 MB  [32][8192]
    float* PcolE  = (float*)(ws + 3145728);        // 2 MB  [64][8192]
    float* S_part = (float*)(ws + 5242880);        // 12.5 MB [256][100][128]
    float* S      = (float*)(ws + 18350080);       // 50 KB [100][128]
    float* hist   = (float*)(ws + 18401280);       // 512 B
    float* bsums  = (float*)(ws + 18401792);       // 128 B
    unsigned* counter = (unsigned*)(ws + 18401920);

    hipMemsetAsync(hist, 0, 512, stream);
    k_norm<<<N / 4, 256, 0, stream>>>(feat, lab, temp, fbf, hist, counter);
    k_csum<<<256, 128, 0, stream>>>(fbf, lab, S_part);
    k_csum2<<<100, 128, 0, stream>>>(S_part, S);
    k_gemm<<<544, 256, 0, stream>>>(fbf, lab, ProwE, PcolE);
    k_tail<<<32, 256, 0, stream>>>(ProwE, PcolE, fbf, lab, S, hist, bsums, counter, out);
}

// Round 9
// 92.163 us; speedup vs baseline: 1.2665x; 1.2665x over previous
//
#include <hip/hip_runtime.h>
#include <hip/hip_bf16.h>

#define N 8192
#define D 128
#define LN2 0.69314718056f

typedef __bf16 bf16x8 __attribute__((ext_vector_type(8)));
typedef float f32x4 __attribute__((ext_vector_type(4)));
typedef unsigned int u32;

// async global->LDS, 16B/lane; LDS dest = wave-uniform base + lane*16,
// global src per-lane (m173: swizzle lives on the SOURCE address).
__device__ __forceinline__ void gload_lds16(const void* g, void* l) {
    __builtin_amdgcn_global_load_lds(
        (const __attribute__((address_space(1))) u32*)g,
        (__attribute__((address_space(3))) u32*)l, 16, 0, 0);
}

// Kernel 1: row-normalize (fp32 -> bf16), pre-scaled by rsqrt(T*ln2) so
// downstream dot products equal logits*log2(e). Zeroes tail counter.
__global__ void k_norm(const float* __restrict__ feat, const float* __restrict__ tempp,
                       __hip_bfloat16* __restrict__ fbf, unsigned* __restrict__ counter) {
    if (blockIdx.x == 0 && threadIdx.x == 0) *counter = 0u;
    const int row  = blockIdx.x * 4 + (threadIdx.x >> 6);
    const int lane = threadIdx.x & 63;
    float2 v = *reinterpret_cast<const float2*>(&feat[row * D + lane * 2]);
    float ss = v.x * v.x + v.y * v.y;
#pragma unroll
    for (int m = 32; m; m >>= 1) ss += __shfl_xor(ss, m);
    const float sc = rsqrtf(tempp[0] * LN2);
    const float r = sc / fmaxf(sqrtf(ss), 1e-8f);
    __hip_bfloat162 o;
    o.x = __float2bfloat16(v.x * r);
    o.y = __float2bfloat16(v.y * r);
    *reinterpret_cast<__hip_bfloat162*>(&fbf[row * D + lane * 2]) = o;
}

// Kernel 2: balanced upper-triangle strips. Block (a,seg): rows [a*128,+128),
// up to 4 tiles b = a+seg*4+t. A-resident, LDS-dbuf B via global_load_lds,
// 1 barrier/tile. Epilogue accumulates BOTH spos (same-label logit sum) and
// edem (diff-label exp sum), each along rows (rows of a -> Prow slabs) and
// cols (rows of b -> Pcol slab a). Diagonal tile: row path only.
__launch_bounds__(256, 2)
__global__ void k_gemm(const __hip_bfloat16* __restrict__ fbf,
                       const int* __restrict__ lab,
                       float* __restrict__ ProwS, float* __restrict__ ProwE,
                       float* __restrict__ PcolS, float* __restrict__ PcolE) {
    __shared__ char Bs[65536];                 // 2 x 32KB B-tile buffers
    __shared__ float redCS[2][2][128];         // [parity][wm][col] spos
    __shared__ float redCE[2][2][128];         // [parity][wm][col] edem

    // decode blockIdx -> (a, seg): group g has a in [4g,4g+4), 16-g segs each
    int bid = blockIdx.x, g = 0;
    while (bid >= 4 * (16 - g)) { bid -= 4 * (16 - g); ++g; }
    const int na = 16 - g;
    int a = 4 * g, seg = bid;
    while (seg >= na) { seg -= na; ++a; }
    const int bstart = a + seg * 4;
    const int nt = min(4, 64 - bstart);

    const int i0 = a * 128;
    const int tid = threadIdx.x;
    const int wave = tid >> 6, lane = tid & 63;
    const int wm = wave >> 1, wn = wave & 1;   // 2x2 waves, 64x64 each
    const int lr = lane & 15, lg = lane >> 4;

    // A fragments resident: rows i0 + wm*64 + mi*16 + lr, k = ks*32 + lg*8
    const __hip_bfloat16* pa = fbf + (size_t)(i0 + wm * 64 + lr) * D + lg * 8;
    bf16x8 af[4][4];
#pragma unroll
    for (int mi = 0; mi < 4; ++mi)
#pragma unroll
        for (int ks = 0; ks < 4; ++ks)
            af[mi][ks] = *reinterpret_cast<const bf16x8*>(pa + mi * 16 * D + ks * 32);

    int4 labi[4];
#pragma unroll
    for (int mi = 0; mi < 4; ++mi)
        labi[mi] = *reinterpret_cast<const int4*>(&lab[i0 + wm * 64 + mi * 16 + lg * 4]);

    float rps[4][4] = {}, res_[4][4] = {};     // row partials (rows of a)

    const char* fbytes = reinterpret_cast<const char*>(fbf);
#define STAGE(t)                                                               \
    {                                                                          \
        const int j0s = (bstart + (t)) * 128;                                  \
        char* dst = Bs + ((t) & 1) * 32768;                                    \
        _Pragma("unroll")                                                      \
        for (int it = 0; it < 8; ++it) {                                       \
            const int base = (it * 4 + wave) * 64;                             \
            const int c_ = base + lane;                                        \
            const int row = c_ >> 4;                                           \
            const int kc = (c_ & 15) ^ (row & 7);                              \
            gload_lds16(fbytes + (size_t)(j0s + row) * 256 + kc * 16,          \
                        dst + base * 16);                                      \
        }                                                                      \
    }

    STAGE(0);
    __syncthreads();

    for (int t = 0; t < nt; ++t) {
        if (t + 1 < nt) STAGE(t + 1);
        const char* buf = Bs + (t & 1) * 32768;
        const int bt = bstart + t;
        const int j0 = bt * 128;
        float cps[2][2] = {}, ces[2][2] = {};  // col partials (this tile)
#pragma unroll
        for (int h = 0; h < 2; ++h) {          // two 32-col halves
            bf16x8 bfr[2][4];
            int labj[2];
#pragma unroll
            for (int nih = 0; nih < 2; ++nih) {
#pragma unroll
                for (int ks = 0; ks < 4; ++ks) {
                    const int R = wn * 64 + h * 32 + nih * 16 + lr;
                    const int kc = ks * 4 + lg;
                    bfr[nih][ks] = *reinterpret_cast<const bf16x8*>(
                        buf + R * 256 + ((kc ^ (R & 7)) << 4));
                }
                labj[nih] = lab[j0 + wn * 64 + h * 32 + nih * 16 + lr];
            }
            f32x4 acc[4][2] = {};
#pragma unroll
            for (int ks = 0; ks < 4; ++ks)
#pragma unroll
                for (int mi = 0; mi < 4; ++mi)
#pragma unroll
                    for (int nih = 0; nih < 2; ++nih)
                        acc[mi][nih] = __builtin_amdgcn_mfma_f32_16x16x32_bf16(
                            af[mi][ks], bfr[nih][ks], acc[mi][nih], 0, 0, 0);
            // C/D layout (m89): col = lane&15, row = (lane>>4)*4 + reg
#pragma unroll
            for (int mi = 0; mi < 4; ++mi)
#pragma unroll
                for (int r = 0; r < 4; ++r) {
                    const int li = reinterpret_cast<const int*>(&labi[mi])[r];
#pragma unroll
                    for (int nih = 0; nih < 2; ++nih) {
                        const float v = acc[mi][nih][r];   // logits * log2(e)
                        const float e = __builtin_amdgcn_exp2f(v);
                        const bool same = (li == labj[nih]);
                        const float sv = same ? v : 0.0f;
                        const float se = same ? 0.0f : e;
                        rps[mi][r]  += sv;  res_[mi][r] += se;   // row path
                        cps[h][nih] += sv;  ces[h][nih] += se;   // col path
                    }
                }
        }
        // col reduce: lanes differing in lg hold different row subsets
#pragma unroll
        for (int h = 0; h < 2; ++h)
#pragma unroll
            for (int nih = 0; nih < 2; ++nih) {
                float cp = cps[h][nih], ce = ces[h][nih];
                cp += __shfl_xor(cp, 16); cp += __shfl_xor(cp, 32);
                ce += __shfl_xor(ce, 16); ce += __shfl_xor(ce, 32);
                if (lg == 0) {
                    const int coll = wn * 64 + h * 32 + nih * 16 + lr;
                    redCS[t & 1][wm][coll] = cp;
                    redCE[t & 1][wm][coll] = ce;
                }
            }
        __syncthreads();   // dbuf handoff + redC visibility
        if (tid < 128 && bt != a) {
            PcolS[(size_t)a * N + j0 + tid] = redCS[t & 1][0][tid] + redCS[t & 1][1][tid];
            PcolE[(size_t)a * N + j0 + tid] = redCE[t & 1][0][tid] + redCE[t & 1][1][tid];
        }
    }
#undef STAGE

    // row partials: reduce over the 16 col-lanes, write per-(seg,wn) slab
#pragma unroll
    for (int mi = 0; mi < 4; ++mi)
#pragma unroll
        for (int r = 0; r < 4; ++r) {
            float ps = rps[mi][r], es = res_[mi][r];
#pragma unroll
            for (int m = 1; m < 16; m <<= 1) {
                ps += __shfl_xor(ps, m);
                es += __shfl_xor(es, m);
            }
            if (lr == 0) {
                const int rowl = wm * 64 + mi * 16 + lg * 4 + r;
                ProwS[(size_t)(seg * 2 + wn) * N + i0 + rowl] = ps;
                ProwE[(size_t)(seg * 2 + wn) * N + i0 + rowl] = es;
            }
        }
}

// Kernel 3 (parallel tail, 32 blocks x 256): per-block LDS label histogram,
// per-row combine over valid slabs, block sums, last-block finalize.
__global__ void k_tail(const float* __restrict__ ProwS, const float* __restrict__ ProwE,
                       const float* __restrict__ PcolS, const float* __restrict__ PcolE,
                       const int* __restrict__ lab,
                       float* __restrict__ bsums, unsigned* __restrict__ counter,
                       float* __restrict__ out) {
    __shared__ float hist[128];
    __shared__ float wsum[4];
    const int tid = threadIdx.x;
    if (tid < 128) hist[tid] = 0.0f;
    __syncthreads();
#pragma unroll
    for (int k = 0; k < 32; ++k) atomicAdd(&hist[lab[tid + k * 256]], 1.0f);
    __syncthreads();

    const int i = blockIdx.x * 256 + tid;
    const int p = i >> 7;                       // panel of row i
    float sp = 0.0f, ed = 0.0f;
    const int ns = 16 - (p >> 2);               // row-slab count for panel p
    for (int s = 0; s < 2 * ns; ++s) {
        sp += ProwS[(size_t)s * N + i];
        ed += ProwE[(size_t)s * N + i];
    }
    for (int aa = 0; aa < p; ++aa) {
        sp += PcolS[(size_t)aa * N + i];
        ed += PcolE[(size_t)aa * N + i];
    }
    float term = LN2 * (sp / hist[lab[i]] - __builtin_amdgcn_logf(ed));  // log2->ln
#pragma unroll
    for (int m = 32; m; m >>= 1) term += __shfl_xor(term, m);
    if ((tid & 63) == 0) wsum[tid >> 6] = term;
    __syncthreads();
    if (tid == 0) {
        bsums[blockIdx.x] = wsum[0] + wsum[1] + wsum[2] + wsum[3];
        __threadfence();
        const unsigned v = atomicAdd(counter, 1u);
        if (v == 31u) {
            __threadfence();
            float tt = 0.0f;
            for (int k = 0; k < 32; ++k) tt += bsums[k];
            out[0] = -(tt / (float)N);
        }
    }
}

extern "C" void kernel_launch(void* const* d_in, const int* in_sizes, int n_in,
                              void* d_out, int out_size, void* d_ws, size_t ws_size,
                              hipStream_t stream) {
    const float* feat = (const float*)d_in[0];
    const int* lab    = (const int*)d_in[1];
    const float* temp = (const float*)d_in[2];
    float* out = (float*)d_out;
    char* ws = (char*)d_ws;

    __hip_bfloat16* fbf = (__hip_bfloat16*)ws;   // 2 MB scaled bf16 features
    float* ProwS = (float*)(ws + 2097152);       // 1 MB [32][8192]
    float* ProwE = (float*)(ws + 3145728);       // 1 MB [32][8192]
    float* PcolS = (float*)(ws + 4194304);       // 2 MB [64][8192]
    float* PcolE = (float*)(ws + 6291456);       // 2 MB [64][8192]
    float* bsums = (float*)(ws + 8388608);       // 128 B
    unsigned* counter = (unsigned*)(ws + 8388736);

    k_norm<<<N / 4, 256, 0, stream>>>(feat, temp, fbf, counter);
    k_gemm<<<544, 256, 0, stream>>>(fbf, lab, ProwS, ProwE, PcolS, PcolE);
    k_tail<<<32, 256, 0, stream>>>(ProwS, ProwE, PcolS, PcolE, lab, bsums, counter, out);
}